// Round 4
// baseline (11591.606 us; speedup 1.0000x reference)
//
#include <hip/hip_runtime.h>
#include <hip/hip_bf16.h>
#include <math.h>

#define N_TOK   131072
#define NE      1024
#define EDIM    256
#define BM      64
#define BN      64
#define BK      64
#define LDK     68      // padded LDS row stride (floats)
#define NTHREADS 256
#define MARGIN  1.0e-4f // > ulp(512)=6.1e-5? no: > ulp(256..512)=3.05e-5 + 2*screen_err(~1.4e-5) w/ 2x safety

// ---------------------------------------------------------------------------
// numpy pairwise sum replica for sum(v*v) over 256 contiguous floats.
// numpy: n=256 -> rec(a,128) + rec(a+128,128); each 128-block: 8 accumulators
// stride 8, combine ((r0+r1)+(r2+r3))+((r4+r5)+(r6+r7)). No FMA contraction.
__device__ __forceinline__ float np_sumsq_256(const float* q) {
    float b[2];
#pragma unroll
    for (int blk = 0; blk < 2; ++blk) {
        const float* a = q + blk * 128;
        float r0 = __fmul_rn(a[0], a[0]), r1 = __fmul_rn(a[1], a[1]);
        float r2 = __fmul_rn(a[2], a[2]), r3 = __fmul_rn(a[3], a[3]);
        float r4 = __fmul_rn(a[4], a[4]), r5 = __fmul_rn(a[5], a[5]);
        float r6 = __fmul_rn(a[6], a[6]), r7 = __fmul_rn(a[7], a[7]);
        for (int i = 8; i < 128; i += 8) {
            r0 = __fadd_rn(r0, __fmul_rn(a[i + 0], a[i + 0]));
            r1 = __fadd_rn(r1, __fmul_rn(a[i + 1], a[i + 1]));
            r2 = __fadd_rn(r2, __fmul_rn(a[i + 2], a[i + 2]));
            r3 = __fadd_rn(r3, __fmul_rn(a[i + 3], a[i + 3]));
            r4 = __fadd_rn(r4, __fmul_rn(a[i + 4], a[i + 4]));
            r5 = __fadd_rn(r5, __fmul_rn(a[i + 5], a[i + 5]));
            r6 = __fadd_rn(r6, __fmul_rn(a[i + 6], a[i + 6]));
            r7 = __fadd_rn(r7, __fmul_rn(a[i + 7], a[i + 7]));
        }
        b[blk] = __fadd_rn(__fadd_rn(__fadd_rn(r0, r1), __fadd_rn(r2, r3)),
                           __fadd_rn(__fadd_rn(r4, r5), __fadd_rn(r6, r7)));
    }
    return __fadd_rn(b[0], b[1]);
}

// ---------------------------------------------------------------------------
// Kernel 0: sw2f[c] = np-replica fp32 of sum(w_c^2). One thread per code row.
__global__ void sw2_np_kernel(const float* __restrict__ w, float* __restrict__ sw2) {
    int row = blockIdx.x * 256 + threadIdx.x;
    sw2[row] = np_sumsq_256(&w[row * EDIM]);
}

// ---------------------------------------------------------------------------
// Kernel 1: screen (fp32, high precision) + fp32-replica rescue on near-ties.
__global__ __launch_bounds__(256, 4) void argmin_kernel(
    const float* __restrict__ x, const float* __restrict__ w,
    const float* __restrict__ sw2, float* __restrict__ zq,
    float* __restrict__ idxo)
{
    __shared__ float xs[BM * LDK];
    __shared__ float wls[BN * LDK];
    __shared__ int   chosen[BM];
    __shared__ int   flags[BM];
    __shared__ float sx2sh;
    __shared__ float rrv[4];
    __shared__ int   rri[4];

    const int t    = threadIdx.x;
    const int tx   = t & 15;
    const int ty   = t >> 4;
    const int row0 = blockIdx.x * BM;

    float bestv[4], secv[4];
    int   besti[4];
#pragma unroll
    for (int i = 0; i < 4; ++i) { bestv[i] = 3.4e38f; secv[i] = 3.4e38f; besti[i] = 0; }

    for (int tile = 0; tile < NE / BN; ++tile) {
        float acc[4][4];
#pragma unroll
        for (int i = 0; i < 4; ++i)
#pragma unroll
            for (int j = 0; j < 4; ++j) acc[i][j] = 0.f;

        for (int kc = 0; kc < EDIM / BK; ++kc) {
#pragma unroll
            for (int p = 0; p < 4; ++p) {
                int g = t + NTHREADS * p;
                int r = g >> 4;
                int f = g & 15;
                float4 xv = *(const float4*)&x[(size_t)(row0 + r) * EDIM + kc * BK + 4 * f];
                *(float4*)&xs[r * LDK + 4 * f] = xv;
                float4 wv = *(const float4*)&w[(tile * BN + r) * EDIM + kc * BK + 4 * f];
                *(float4*)&wls[r * LDK + 4 * f] = wv;
            }
            __syncthreads();
#pragma unroll
            for (int k4 = 0; k4 < BK / 4; ++k4) {
                float4 xv[4], wv[4];
#pragma unroll
                for (int i = 0; i < 4; ++i)
                    xv[i] = *(const float4*)&xs[(ty + 16 * i) * LDK + 4 * k4];
#pragma unroll
                for (int j = 0; j < 4; ++j)
                    wv[j] = *(const float4*)&wls[(tx + 16 * j) * LDK + 4 * k4];
#pragma unroll
                for (int i = 0; i < 4; ++i)
#pragma unroll
                    for (int j = 0; j < 4; ++j)
                        acc[i][j] += xv[i].x * wv[j].x + xv[i].y * wv[j].y
                                   + xv[i].z * wv[j].z + xv[i].w * wv[j].w;
            }
            __syncthreads();
        }
#pragma unroll
        for (int j = 0; j < 4; ++j) {
            int c = tile * BN + tx + 16 * j;
            float s2 = sw2[c];
#pragma unroll
            for (int i = 0; i < 4; ++i) {
                float d = s2 - 2.f * acc[i][j];
                if (d < bestv[i]) { secv[i] = bestv[i]; bestv[i] = d; besti[i] = c; }
                else if (d < secv[i]) secv[i] = d;
            }
        }
    }

    // merge (best, idx, second) across 16 tx lanes (same wave)
#pragma unroll
    for (int i = 0; i < 4; ++i) {
        float v  = bestv[i], s = secv[i];
        int   bi = besti[i];
#pragma unroll
        for (int off = 8; off > 0; off >>= 1) {
            float ov = __shfl_down(v, off, 16);
            float os = __shfl_down(s, off, 16);
            int   oi = __shfl_down(bi, off, 16);
            if (ov < v || (ov == v && oi < bi)) { s = fminf(os, v); v = ov; bi = oi; }
            else                                { s = fminf(s, ov); }
        }
        if (tx == 0) {
            int r = ty + 16 * i;
            chosen[r] = bi;
            flags[r]  = (s - v < MARGIN) ? 1 : 0;
            idxo[row0 + r] = (float)bi;
        }
    }
    __syncthreads();

    // ---- rescue: bit-replicate the fp32 reference formula over all codes ----
    const int lane = t & 63, wvid = t >> 6;
    for (int r = 0; r < BM; ++r) {
        if (flags[r]) {
            xs[t] = x[(size_t)(row0 + r) * EDIM + t];   // stage x row
            __syncthreads();
            if (t == 0) sx2sh = np_sumsq_256(xs);       // np pairwise replica
            __syncthreads();
            const float sx2f = sx2sh;
            float bestd = 3.4e38f;
            int   bestc = 0;
#pragma unroll
            for (int jj = 0; jj < 4; ++jj) {
                int c = jj * 256 + t;
                const float4* wc = (const float4*)&w[c * EDIM];
                double acc = 0.0;
                for (int k4 = 0; k4 < 64; ++k4) {
                    float4 wv = wc[k4];
                    float4 xv = *(const float4*)&xs[4 * k4];
                    acc = fma((double)wv.x, (double)xv.x, acc);
                    acc = fma((double)wv.y, (double)xv.y, acc);
                    acc = fma((double)wv.z, (double)xv.z, acc);
                    acc = fma((double)wv.w, (double)xv.w, acc);
                }
                float m  = (float)acc;                       // sgemm value (exact-rounded)
                float t1 = __fadd_rn(sx2f, sw2[c]);          // (sx2 + sw2) fp32
                float d  = __fsub_rn(t1, __fmul_rn(2.0f, m));// ... - 2*m  fp32
                if (d < bestd) { bestd = d; bestc = c; }     // jj asc -> low c on ties
            }
#pragma unroll
            for (int off = 32; off > 0; off >>= 1) {
                float od = __shfl_down(bestd, off, 64);
                int   oc = __shfl_down(bestc, off, 64);
                if (od < bestd || (od == bestd && oc < bestc)) { bestd = od; bestc = oc; }
            }
            if (lane == 0) { rrv[wvid] = bestd; rri[wvid] = bestc; }
            __syncthreads();
            if (t == 0) {
                float bv = rrv[0]; int bi = rri[0];
#pragma unroll
                for (int q = 1; q < 4; ++q)
                    if (rrv[q] < bv || (rrv[q] == bv && rri[q] < bi)) { bv = rrv[q]; bi = rri[q]; }
                chosen[r] = bi;
                idxo[row0 + r] = (float)bi;
            }
            __syncthreads();
        }
    }
    __syncthreads();

    // ---- gather z_q rows ----
    const int rr = t >> 6;
    const int f  = t & 63;
#pragma unroll 4
    for (int p = 0; p < 16; ++p) {
        int r  = p * 4 + rr;
        int ci = chosen[r];
        float4 v = *(const float4*)&w[ci * EDIM + 4 * f];
        *(float4*)&zq[(size_t)(row0 + r) * EDIM + 4 * f] = v;
    }
}

// ---------------------------------------------------------------------------
__global__ __launch_bounds__(256) void ce_kernel(const float* __restrict__ w,
                                                 float* __restrict__ rowres) {
    __shared__ float wj[4 * EDIM];
    __shared__ float redsum[4 * 4];
    __shared__ float diagl[4];

    const int t  = threadIdx.x;
    const int j0 = blockIdx.x * 4;
    {
        int r = t >> 6, f = t & 63;
        *(float4*)&wj[r * EDIM + 4 * f] = *(const float4*)&w[(j0 + r) * EDIM + 4 * f];
    }
    __syncthreads();

    float se[4] = {0.f, 0.f, 0.f, 0.f};
    for (int kk = 0; kk < 4; ++kk) {
        int k = kk * 256 + t;
        const float4* wk = (const float4*)&w[k * EDIM];
        float d[4] = {0.f, 0.f, 0.f, 0.f};
        for (int f = 0; f < 64; ++f) {
            float4 v = wk[f];
#pragma unroll
            for (int r = 0; r < 4; ++r) {
                float4 a = *(const float4*)&wj[r * EDIM + 4 * f];
                d[r] += a.x * v.x + a.y * v.y + a.z * v.z + a.w * v.w;
            }
        }
#pragma unroll
        for (int r = 0; r < 4; ++r) {
            float l = 3.f * d[r];
            se[r] += expf(l);
            if (k == j0 + r) diagl[r] = l;
        }
    }
    const int lane = t & 63, wv = t >> 6;
#pragma unroll
    for (int r = 0; r < 4; ++r) {
        float s = se[r];
#pragma unroll
        for (int off = 32; off > 0; off >>= 1) s += __shfl_down(s, off, 64);
        if (lane == 0) redsum[r * 4 + wv] = s;
    }
    __syncthreads();
    if (t < 4) {
        float S = redsum[t * 4 + 0] + redsum[t * 4 + 1]
                + redsum[t * 4 + 2] + redsum[t * 4 + 3];
        rowres[j0 + t] = diagl[t] - logf(S);
    }
}

// ---------------------------------------------------------------------------
__global__ void loss_final(const float* __restrict__ rowres,
                           const int* __restrict__ idxp,
                           float* __restrict__ lossp) {
    __shared__ float red[4];
    const int t = threadIdx.x;
    float s = rowres[t] + rowres[t + 256] + rowres[t + 512] + rowres[t + 768];
    const int lane = t & 63, wv = t >> 6;
#pragma unroll
    for (int off = 32; off > 0; off >>= 1) s += __shfl_down(s, off, 64);
    if (lane == 0) red[wv] = s;
    __syncthreads();
    if (t == 0) {
        float tot = red[0] + red[1] + red[2] + red[3];
        float ce = -(tot / 1024.f);
        float loss = (*idxp == 0) ? ce : 0.f;
        *lossp = loss;
    }
}

// ---------------------------------------------------------------------------
extern "C" void kernel_launch(void* const* d_in, const int* in_sizes, int n_in,
                              void* d_out, int out_size, void* d_ws, size_t ws_size,
                              hipStream_t stream) {
    (void)in_sizes; (void)n_in; (void)out_size; (void)ws_size;
    const float* x   = (const float*)d_in[0];
    const float* w   = (const float*)d_in[1];
    const int*   idx = (const int*)d_in[2];

    float* outf  = (float*)d_out;
    float* zq    = outf;                                 // 131072*256 f32
    float* idxo  = outf + (size_t)N_TOK * EDIM;          // 131072 f32
    float* lossp = idxo + N_TOK;                         // 1 f32

    float* sw2    = (float*)d_ws;
    float* rowres = sw2 + 1024;

    sw2_np_kernel<<<NE / 256, 256, 0, stream>>>(w, sw2);
    argmin_kernel<<<N_TOK / BM, NTHREADS, 0, stream>>>(x, w, sw2, zq, idxo);
    ce_kernel<<<NE / 4, 256, 0, stream>>>(w, rowres);
    loss_final<<<1, 256, 0, stream>>>(rowres, idx, lossp);
}